// Round 9
// baseline (174.004 us; speedup 1.0000x reference)
//
#include <hip/hip_runtime.h>
#include <hip/hip_bf16.h>

// Problem constants
#define NTOT 3060     // 2304 + 576 + 144 + 36 tokens across 4 scales
#define NPIX 2304     // 48*48
#define CH   256
#define NLN  589824   // 256*48*48
#define VSTR 3072     // padded row stride (tokens) for V^T bf16

// ws float offsets (ws is 256 MiB; no overlays, all regions disjoint)
#define XST_OFF   0         // xsT bf16 [3060][256]   (391680 f32 as u16 x2)
#define WB_OFF    400000    // Wb bf16 4x[256][256]   (131072 f32)
#define QBF_OFF   600000    // Qbf bf16 [8][3060][32] (391680)
#define KBF_OFF   1000000   // Kbf bf16
#define VT_OFF    1400000   // Vt bf16 [256][3072]    (393216)
#define OBF_OFF   1800000   // Obf bf16 [3060][256]   (391680)
#define YB_OFF    2200000   // Yb fp32 [256][3060]    (783360)
#define OUTA_OFF  3000000   // outa fp32 [256][2304]  (589824)
#define ST_OFF    3600000   // st 5x256
#define CW_OFF    3601280
#define SCAL_OFF  3601536
// split-K partials: scale0 8-way, scale1 4-way
#define P0_OFF    4000000   // 8*8*2304*32 = 4718592
#define PM0_OFF   8718592   // 147456
#define PL0_OFF   8866048   // 147456
#define P1_OFF    9100000   // 4*8*576*32 = 589824
#define PM1_OFF   9700000   // 18432
#define PL1_OFF   9718432   // 18432 (ends 9736864 << 67M floats)

typedef __attribute__((ext_vector_type(8))) short bf16x8;
typedef __attribute__((ext_vector_type(16))) float f32x16;

__device__ __forceinline__ bf16x8 ldfrag(const unsigned short* p) {
  int4 v = *reinterpret_cast<const int4*>(p);
  return __builtin_bit_cast(bf16x8, v);
}
// round-to-nearest-even f32 -> bf16
__device__ __forceinline__ unsigned f2bf(float f) {
  unsigned u = __builtin_bit_cast(unsigned, f);
  return (u + 0x7FFFu + ((u >> 16) & 1u)) >> 16;
}
__device__ __forceinline__ unsigned pk2(float a, float b) {
  return f2bf(a) | (f2bf(b) << 16);
}
#define MFMA32(a, b, c) __builtin_amdgcn_mfma_f32_32x32x16_bf16((a), (b), (c), 0, 0, 0)

// ---------------------------------------------------------------------------
// K1: fused prologue. Blocks [0,512): cast W fp32->bf16 (Wq|Wk|Wv|Wfc).
// Blocks [512,704): downsample x -> xsT [token][256] bf16.
// ---------------------------------------------------------------------------
__global__ __launch_bounds__(256) void k_pre(const float* __restrict__ Wq,
                                             const float* __restrict__ Wk,
                                             const float* __restrict__ Wv,
                                             const float* __restrict__ Wfc,
                                             const float* __restrict__ x,
                                             unsigned* __restrict__ Wb,
                                             unsigned short* __restrict__ xsT) {
  int b = blockIdx.x, t = threadIdx.x;
  if (b < 512) {
    int i = b * 256 + t;                      // u32 index, total 131072
    int m = i >> 15;
    int r = i & 32767;
    const float* src = (m == 0) ? Wq : (m == 1) ? Wk : (m == 2) ? Wv : Wfc;
    float2 v = *(const float2*)&src[(size_t)r * 2];
    Wb[i] = pk2(v.x, v.y);
    return;
  }
  int bx = b - 512;                           // 0..191 = 48 token-tiles x 4 ch-tiles
  int n = (bx % 48) * 64 + (t & 63);
  int cb = (bx / 48) * 64 + (t >> 6) * 16;
  if (n >= NTOT) return;
  int p, Ws, s;
  if (n < 2304)      { s = 0; p = n;        Ws = 48; }
  else if (n < 2880) { s = 1; p = n - 2304; Ws = 24; }
  else if (n < 3024) { s = 2; p = n - 2880; Ws = 12; }
  else               { s = 3; p = n - 3024; Ws = 6;  }
  int oy = p / Ws, ox = p - oy * Ws;
  int b0; bool avg = (s != 0);
  if (s == 0) b0 = p;
  else {
    int r, cc;
    if (s == 1)      { r = 2 * oy;     cc = 2 * ox;     }
    else if (s == 2) { r = 4 * oy + 1; cc = 4 * ox + 1; }
    else             { r = 8 * oy + 3; cc = 8 * ox + 3; }
    b0 = r * 48 + cc;
  }
#pragma unroll
  for (int i0 = 0; i0 < 16; i0 += 8) {
    unsigned u[4];
#pragma unroll
    for (int jj = 0; jj < 4; jj++) {
      float v[2];
#pragma unroll
      for (int e = 0; e < 2; e++) {
        int c = cb + i0 + jj * 2 + e;
        const float* xc = x + (size_t)c * NPIX;
        v[e] = avg ? 0.25f * (xc[b0] + xc[b0 + 1] + xc[b0 + 48] + xc[b0 + 49])
                   : xc[b0];
      }
      u[jj] = pk2(v[0], v[1]);
    }
    *(int4*)&xsT[(size_t)n * 256 + cb + i0] = make_int4((int)u[0], (int)u[1],
                                                        (int)u[2], (int)u[3]);
  }
}

// ---------------------------------------------------------------------------
// K2: QKV GEMM via MFMA. Register-only; wave = 32j x 32n tile, K=256.
// z=0 -> Qbf [h][n][32], z=1 -> Kbf, z=2 -> Vt [j][VSTR] (bf16).
// ---------------------------------------------------------------------------
__global__ __launch_bounds__(256) void k_qkv_mfma(const unsigned short* __restrict__ Wb,
                                                  const float* __restrict__ bq,
                                                  const float* __restrict__ bk,
                                                  const float* __restrict__ bv,
                                                  const unsigned short* __restrict__ xsT,
                                                  unsigned short* __restrict__ Qbf,
                                                  unsigned short* __restrict__ Kbf,
                                                  unsigned short* __restrict__ Vt) {
  int z = blockIdx.z, h = blockIdx.y;
  int j0 = h * 32;
  const unsigned short* W = Wb + (size_t)z * 65536;
  const float* bias = (z == 0) ? bq : (z == 1) ? bk : bv;
  int t = threadIdx.x, w = t >> 6, l = t & 63, lq = l & 31, h2 = l >> 5;
  int n = blockIdx.x * 128 + w * 32 + lq;
  int nc = min(n, NTOT - 1);

  bf16x8 bfr[16];
#pragma unroll
  for (int kk = 0; kk < 16; kk++)
    bfr[kk] = ldfrag(&xsT[(size_t)nc * 256 + kk * 16 + h2 * 8]);

  f32x16 acc = {0,0,0,0,0,0,0,0,0,0,0,0,0,0,0,0};
#pragma unroll
  for (int kk = 0; kk < 16; kk++) {
    bf16x8 af = ldfrag(&W[(size_t)(j0 + lq) * 256 + kk * 16 + h2 * 8]);
    acc = MFMA32(af, bfr[kk], acc);
  }

  float4 bi[4];
#pragma unroll
  for (int g = 0; g < 4; g++) bi[g] = *(const float4*)&bias[j0 + 4 * h2 + 8 * g];

  if (n < NTOT) {
    if (z < 2) {
      unsigned short* dst = ((z == 0) ? Qbf : Kbf) + ((size_t)h * NTOT + n) * 32;
#pragma unroll
      for (int g = 0; g < 4; g++) {
        unsigned p0 = pk2(acc[4 * g + 0] + bi[g].x, acc[4 * g + 1] + bi[g].y);
        unsigned p1 = pk2(acc[4 * g + 2] + bi[g].z, acc[4 * g + 3] + bi[g].w);
        *(int2*)&dst[4 * h2 + 8 * g] = make_int2((int)p0, (int)p1);
      }
    } else {
#pragma unroll
      for (int g = 0; g < 4; g++) {
        float bb[4] = {bi[g].x, bi[g].y, bi[g].z, bi[g].w};
#pragma unroll
        for (int q = 0; q < 4; q++) {
          int d = 4 * h2 + 8 * g + q;
          Vt[(size_t)(j0 + d) * VSTR + n] = (unsigned short)f2bf(acc[4 * g + q] + bb[q]);
        }
      }
    }
  }
}

// ---------------------------------------------------------------------------
// K3: bf16 MFMA flash attention with split-K (8-way sc0, 4-way sc1).
// Whole-scale blocks write O^T directly to Obf [token][256] bf16;
// split blocks write fp32 partials, merged by k_combine.
// ---------------------------------------------------------------------------
__global__ __launch_bounds__(256) void k_attn_mfma(const unsigned short* __restrict__ Qbf,
                                                   const unsigned short* __restrict__ Kbf,
                                                   const unsigned short* __restrict__ Vt,
                                                   unsigned short* __restrict__ Obf,
                                                   float* __restrict__ wsf) {
  const int Ns_tab[4]  = {2304, 576, 144, 36};
  const int off_tab[4] = {0, 2304, 2880, 3024};

  int bid = blockIdx.x;
  int sc, head, qt, sp, nsp;
  if (bid < 1152)      { int qtb = bid >> 3; sp = bid & 7; nsp = 8; sc = 0; head = qtb / 18; qt = qtb - head * 18; }
  else if (bid < 1312) { int b = bid - 1152; int qtb = b >> 2; sp = b & 3; nsp = 4; sc = 1; head = qtb / 5; qt = qtb - head * 5; }
  else if (bid < 1328) { int b = bid - 1312; sc = 2; head = b >> 1; qt = b & 1; sp = 0; nsp = 1; }
  else                 { sc = 3; head = bid - 1328; qt = 0; sp = 0; nsp = 1; }

  int Ns = Ns_tab[sc], off = off_tab[sc];
  int t = threadIdx.x;
  int w = t >> 6, l = t & 63;
  int lq = l & 31, h2 = l >> 5;
  int qbase = qt * 128 + w * 32;
  if (qbase >= Ns) return;

  int chunk = Ns / nsp;                 // sc0: 288, sc1: 144
  int kbeg = sp * chunk, kend = kbeg + chunk;

  const unsigned short* Qh = Qbf + ((size_t)head * NTOT + off) * 32;
  const unsigned short* Kh = Kbf + ((size_t)head * NTOT + off) * 32;
  const unsigned short* Vh = Vt + (size_t)(head * 32) * VSTR + off;

  int qc = qbase + lq; if (qc >= Ns) qc = Ns - 1;
  const unsigned short* Qp = Qh + (size_t)qc * 32 + h2 * 8;
  bf16x8 qf0 = ldfrag(Qp);
  bf16x8 qf1 = ldfrag(Qp + 16);

  float m = -3.0e38f, L = 0.f;
  f32x16 oacc = {0,0,0,0,0,0,0,0,0,0,0,0,0,0,0,0};

  int mt0 = kbeg + lq; if (mt0 >= Ns) mt0 = Ns - 1;
  const unsigned short* Kp0 = Kh + (size_t)mt0 * 32 + h2 * 8;
  bf16x8 kf0n = ldfrag(Kp0);
  bf16x8 kf1n = ldfrag(Kp0 + 16);

  for (int kb = kbeg; kb < kend; kb += 32) {
    bf16x8 kf0 = kf0n, kf1 = kf1n;
    const unsigned short* Vp = Vh + (size_t)lq * VSTR + kb + h2 * 8;
    bf16x8 vf0 = ldfrag(Vp);
    bf16x8 vf1 = ldfrag(Vp + 16);
    int kb2 = kb + 32;
    if (kb2 < kend) {
      int mt = kb2 + lq; if (mt >= Ns) mt = Ns - 1;
      const unsigned short* Kp = Kh + (size_t)mt * 32 + h2 * 8;
      kf0n = ldfrag(Kp);
      kf1n = ldfrag(Kp + 16);
    }

    f32x16 sa = {0,0,0,0,0,0,0,0,0,0,0,0,0,0,0,0};
    sa = MFMA32(kf0, qf0, sa);
    sa = MFMA32(kf1, qf1, sa);

    float s[16];
#pragma unroll
    for (int r = 0; r < 16; r++) s[r] = sa[r];
    int rem = kend - kb;
    if (rem < 32) {
#pragma unroll
      for (int r = 0; r < 16; r++) {
        int ko = (r & 3) + 8 * (r >> 2) + 4 * h2;
        if (ko >= rem) s[r] = -3.0e38f;
      }
    }
    float cm = s[0];
#pragma unroll
    for (int r = 1; r < 16; r++) cm = fmaxf(cm, s[r]);
    cm = fmaxf(cm, __shfl_xor(cm, 32));
    float mn = fmaxf(m, cm);
    float scl = __expf(m - mn);
    m = mn;
    L *= scl;
#pragma unroll
    for (int r = 0; r < 16; r++) oacc[r] *= scl;

    float p[16], ls = 0.f;
#pragma unroll
    for (int r = 0; r < 16; r++) { p[r] = __expf(s[r] - m); ls += p[r]; }
    ls += __shfl_xor(ls, 32);
    L += ls;

    unsigned u[8], su[8];
#pragma unroll
    for (int g = 0; g < 8; g++) u[g] = pk2(p[2 * g], p[2 * g + 1]);
#pragma unroll
    for (int g = 0; g < 8; g++) su[g] = __shfl_xor(u[g], 32);

    int4 w0, w1;
    if (h2 == 0) {
      w0 = make_int4((int)u[0], (int)u[1], (int)su[0], (int)su[1]);
      w1 = make_int4((int)u[4], (int)u[5], (int)su[4], (int)su[5]);
    } else {
      w0 = make_int4((int)su[2], (int)su[3], (int)u[2], (int)u[3]);
      w1 = make_int4((int)su[6], (int)su[7], (int)u[6], (int)u[7]);
    }
    bf16x8 pf0 = __builtin_bit_cast(bf16x8, w0);
    bf16x8 pf1 = __builtin_bit_cast(bf16x8, w1);

    oacc = MFMA32(vf0, pf0, oacc);
    oacc = MFMA32(vf1, pf1, oacc);
  }

  int q = qbase + lq;
  if (q < Ns) {
    if (nsp == 1) {
      float rl = 1.f / L;
      unsigned short* dst = Obf + (size_t)(off + q) * 256 + head * 32;
#pragma unroll
      for (int g = 0; g < 4; g++) {
        unsigned p0 = pk2(oacc[4 * g + 0] * rl, oacc[4 * g + 1] * rl);
        unsigned p1 = pk2(oacc[4 * g + 2] * rl, oacc[4 * g + 3] * rl);
        *(int2*)&dst[4 * h2 + 8 * g] = make_int2((int)p0, (int)p1);
      }
    } else {
      int qs = (sc == 0) ? 2304 : 576;
      float* P  = (sc == 0) ? wsf + P0_OFF  : wsf + P1_OFF;
      float* Pm = (sc == 0) ? wsf + PM0_OFF : wsf + PM1_OFF;
      float* PL = (sc == 0) ? wsf + PL0_OFF : wsf + PL1_OFF;
      size_t row = (size_t)(sp * 8 + head) * qs + q;
      float* Prow = P + row * 32;
#pragma unroll
      for (int g = 0; g < 4; g++) {
        float4 v = make_float4(oacc[4 * g + 0], oacc[4 * g + 1],
                               oacc[4 * g + 2], oacc[4 * g + 3]);
        *(float4*)&Prow[g * 8 + 4 * h2] = v;
      }
      if (h2 == 0) { Pm[row] = m; PL[row] = L; }
    }
  }
}

// ---------------------------------------------------------------------------
// K3b: combine split-K partials -> Obf [token][256] bf16 (8 / 4 splits)
// ---------------------------------------------------------------------------
__global__ __launch_bounds__(256) void k_combine(const float* __restrict__ wsf,
                                                 unsigned short* __restrict__ Obf) {
  int tid = blockIdx.x * 256 + threadIdx.x;
  int h, q, off, nsp, qs;
  const float* P; const float* Pm; const float* PL;
  if (tid < 18432) {
    h = tid / 2304; q = tid - h * 2304; off = 0; nsp = 8; qs = 2304;
    P = wsf + P0_OFF; Pm = wsf + PM0_OFF; PL = wsf + PL0_OFF;
  } else if (tid < 23040) {
    int b = tid - 18432;
    h = b / 576; q = b - h * 576; off = 2304; nsp = 4; qs = 576;
    P = wsf + P1_OFF; Pm = wsf + PM1_OFF; PL = wsf + PL1_OFF;
  } else return;

  float mv[8], lv[8];
  float M = -3.0e38f;
  for (int s = 0; s < nsp; s++) {
    size_t row = (size_t)(s * 8 + h) * qs + q;
    mv[s] = Pm[row]; lv[s] = PL[row];
    M = fmaxf(M, mv[s]);
  }
  float e[8], denom = 0.f;
  for (int s = 0; s < nsp; s++) { e[s] = __expf(mv[s] - M); denom += e[s] * lv[s]; }
  float rden = 1.f / denom;

  unsigned short* dst = Obf + (size_t)(off + q) * 256 + h * 32;
#pragma unroll
  for (int d4 = 0; d4 < 8; d4++) {
    float4 acc = make_float4(0.f, 0.f, 0.f, 0.f);
    for (int s = 0; s < nsp; s++) {
      size_t row = (size_t)(s * 8 + h) * qs + q;
      float4 v = *(const float4*)&P[row * 32 + d4 * 4];
      acc.x += e[s] * v.x; acc.y += e[s] * v.y;
      acc.z += e[s] * v.z; acc.w += e[s] * v.w;
    }
    unsigned p0 = pk2(acc.x * rden, acc.y * rden);
    unsigned p1 = pk2(acc.z * rden, acc.w * rden);
    *(int2*)&dst[d4 * 4] = make_int2((int)p0, (int)p1);
  }
}

// ---------------------------------------------------------------------------
// K4: FC GEMM via MFMA: Yb[j][n] = sum_c Wfc[j][c]*O[c][n] + bfc[j] (fp32)
// ---------------------------------------------------------------------------
__global__ __launch_bounds__(256) void k_fc_mfma(const unsigned short* __restrict__ Wfcb,
                                                 const float* __restrict__ bfc,
                                                 const unsigned short* __restrict__ Obf,
                                                 float* __restrict__ Yb) {
  int j0 = blockIdx.y * 32;
  int t = threadIdx.x, w = t >> 6, l = t & 63, lq = l & 31, h2 = l >> 5;
  int n = blockIdx.x * 128 + w * 32 + lq;
  int nc = min(n, NTOT - 1);

  bf16x8 bfr[16];
#pragma unroll
  for (int kk = 0; kk < 16; kk++)
    bfr[kk] = ldfrag(&Obf[(size_t)nc * 256 + kk * 16 + h2 * 8]);

  f32x16 acc = {0,0,0,0,0,0,0,0,0,0,0,0,0,0,0,0};
#pragma unroll
  for (int kk = 0; kk < 16; kk++) {
    bf16x8 af = ldfrag(&Wfcb[(size_t)(j0 + lq) * 256 + kk * 16 + h2 * 8]);
    acc = MFMA32(af, bfr[kk], acc);
  }

  float4 bi[4];
#pragma unroll
  for (int g = 0; g < 4; g++) bi[g] = *(const float4*)&bfc[j0 + 4 * h2 + 8 * g];

  if (n < NTOT) {
#pragma unroll
    for (int g = 0; g < 4; g++) {
      float bb[4] = {bi[g].x, bi[g].y, bi[g].z, bi[g].w};
#pragma unroll
      for (int q = 0; q < 4; q++) {
        int d = 4 * h2 + 8 * g + q;
        Yb[(size_t)(j0 + d) * NTOT + n] = acc[4 * g + q] + bb[q];
      }
    }
  }
}

// ---------------------------------------------------------------------------
// K5: fused upsample-accumulate + per-channel stats (block per channel)
// ---------------------------------------------------------------------------
__device__ __forceinline__ float bil4(const float* __restrict__ a, int S,
                                      int y, int x, float scale, float tr) {
  float fy = fmaf((float)y, scale, tr);
  float fx = fmaf((float)x, scale, tr);
  int iy = (int)floorf(fy); float wy = fy - (float)iy;
  int ix = (int)floorf(fx); float wx = fx - (float)ix;
  int y0 = min(max(iy, 0), S - 1);
  int y1 = min(max(iy + 1, 0), S - 1);
  int x0 = min(max(ix, 0), S - 1);
  int x1 = min(max(ix + 1, 0), S - 1);
  float v00 = a[y0 * S + x0], v01 = a[y0 * S + x1];
  float v10 = a[y1 * S + x0], v11 = a[y1 * S + x1];
  float top = v00 + wx * (v01 - v00);
  float bot = v10 + wx * (v11 - v10);
  return top + wy * (bot - top);
}

__global__ __launch_bounds__(256) void k_upstats(const float* __restrict__ Yb,
                                                 const float* __restrict__ x,
                                                 float* __restrict__ outa,
                                                 float* __restrict__ st) {
  int c = blockIdx.x, t = threadIdx.x;
  const float* Yc = Yb + (size_t)c * NTOT;
  const float* xc = x + (size_t)c * NPIX;
  float so = 0.f, soo = 0.f, sox = 0.f, sx = 0.f, sxx = 0.f;
#pragma unroll
  for (int i = 0; i < 9; i++) {
    int p = t + i * 256;
    int y = p / 48, xx = p - y * 48;
    float v = Yc[p];
    v += bil4(Yc + 2304, 24, y, xx, 0.5f,   -0.25f);
    v += bil4(Yc + 2880, 12, y, xx, 0.25f,  -0.375f);
    v += bil4(Yc + 3024, 6,  y, xx, 0.125f, -0.4375f);
    outa[(size_t)c * NPIX + p] = v;
    float xv = xc[p];
    so += v; soo += v * v; sox += v * xv; sx += xv; sxx += xv * xv;
  }
#pragma unroll
  for (int off = 32; off > 0; off >>= 1) {
    so  += __shfl_down(so, off, 64);
    soo += __shfl_down(soo, off, 64);
    sox += __shfl_down(sox, off, 64);
    sx  += __shfl_down(sx, off, 64);
    sxx += __shfl_down(sxx, off, 64);
  }
  __shared__ float part[4][5];
  int wv = t >> 6;
  if ((t & 63) == 0) {
    part[wv][0] = so; part[wv][1] = soo; part[wv][2] = sox;
    part[wv][3] = sx; part[wv][4] = sxx;
  }
  __syncthreads();
  if (t == 0) {
    float a0 = 0.f, a1 = 0.f, a2 = 0.f, a3 = 0.f, a4 = 0.f;
#pragma unroll
    for (int wi = 0; wi < 4; wi++) {
      a0 += part[wi][0]; a1 += part[wi][1]; a2 += part[wi][2];
      a3 += part[wi][3]; a4 += part[wi][4];
    }
    st[c] = a0; st[256 + c] = a1; st[512 + c] = a2; st[768 + c] = a3; st[1024 + c] = a4;
  }
}

// ---------------------------------------------------------------------------
// K6: SE MLP + analytic LN stats
// ---------------------------------------------------------------------------
__global__ __launch_bounds__(256) void k_se(const float* __restrict__ st,
                                            const float* __restrict__ w1,
                                            const float* __restrict__ b1,
                                            const float* __restrict__ a1,
                                            const float* __restrict__ w2,
                                            const float* __restrict__ b2,
                                            float* __restrict__ cw,
                                            float* __restrict__ scal) {
  __shared__ float avg_s[256];
  __shared__ float h_s[16];
  __shared__ float rS[4], rSS[4];
  int t = threadIdx.x;
  float avg = st[t] * (1.f / (float)NPIX);
  avg_s[t] = avg;
  __syncthreads();
  int i = t >> 4, pp = t & 15;
  float partial = 0.f;
  for (int c = pp; c < 256; c += 16) partial += avg_s[c] * w1[i * 256 + c];
#pragma unroll
  for (int off = 8; off > 0; off >>= 1) partial += __shfl_down(partial, off, 16);
  if (pp == 0) {
    float hv = partial + b1[i];
    float al = a1[0];
    h_s[i] = hv > 0.f ? hv : al * hv;
  }
  __syncthreads();
  float s2 = b2[t];
#pragma unroll
  for (int k = 0; k < 16; k++) s2 += h_s[k] * w2[t * 16 + k];
  float cwv = 1.f / (1.f + expf(-s2));
  cw[t] = cwv;

  float S_part  = cwv * st[t] + st[768 + t];
  float SS_part = cwv * cwv * st[256 + t] + 2.f * cwv * st[512 + t] + st[1024 + t];
#pragma unroll
  for (int off = 32; off > 0; off >>= 1) {
    S_part  += __shfl_down(S_part, off, 64);
    SS_part += __shfl_down(SS_part, off, 64);
  }
  if ((t & 63) == 0) { rS[t >> 6] = S_part; rSS[t >> 6] = SS_part; }
  __syncthreads();
  if (t == 0) {
    float S = rS[0] + rS[1] + rS[2] + rS[3];
    float SS = rSS[0] + rSS[1] + rSS[2] + rSS[3];
    float mu = S / (float)NLN;
    float var = SS / (float)NLN - mu * mu;
    scal[0] = mu;
    scal[1] = rsqrtf(var + 1e-5f);
  }
}

// ---------------------------------------------------------------------------
// K7: final elementwise: gate + residual + layernorm + prelu
// ---------------------------------------------------------------------------
__global__ __launch_bounds__(256) void k_final(const float* __restrict__ outa,
                                               const float* __restrict__ x,
                                               const float* __restrict__ cw,
                                               const float* __restrict__ scal,
                                               const float* __restrict__ a2,
                                               float* __restrict__ out) {
  int idx = blockIdx.x * 256 + threadIdx.x;
  if (idx >= NLN) return;
  int c = idx / NPIX;
  float g = outa[idx] * cw[c] + x[idx];
  float v = (g - scal[0]) * scal[1];
  float al = a2[0];
  out[idx] = v > 0.f ? v : al * v;
}

// ---------------------------------------------------------------------------
extern "C" void kernel_launch(void* const* d_in, const int* in_sizes, int n_in,
                              void* d_out, int out_size, void* d_ws, size_t ws_size,
                              hipStream_t stream) {
  const float* x   = (const float*)d_in[0];
  const float* Wq  = (const float*)d_in[1];
  const float* bq  = (const float*)d_in[2];
  const float* Wk  = (const float*)d_in[3];
  const float* bk  = (const float*)d_in[4];
  const float* Wv  = (const float*)d_in[5];
  const float* bv  = (const float*)d_in[6];
  const float* Wfc = (const float*)d_in[7];
  const float* bfc = (const float*)d_in[8];
  const float* w1  = (const float*)d_in[9];
  const float* b1  = (const float*)d_in[10];
  const float* a1  = (const float*)d_in[11];
  const float* w2  = (const float*)d_in[12];
  const float* b2  = (const float*)d_in[13];
  const float* a2  = (const float*)d_in[14];

  float* wsf = (float*)d_ws;
  unsigned short* xsT = (unsigned short*)(wsf + XST_OFF);
  unsigned short* Wb  = (unsigned short*)(wsf + WB_OFF);
  unsigned short* Qbf = (unsigned short*)(wsf + QBF_OFF);
  unsigned short* Kbf = (unsigned short*)(wsf + KBF_OFF);
  unsigned short* Vt  = (unsigned short*)(wsf + VT_OFF);
  unsigned short* Obf = (unsigned short*)(wsf + OBF_OFF);
  float* Yb   = wsf + YB_OFF;
  float* outa = wsf + OUTA_OFF;
  float* st   = wsf + ST_OFF;
  float* cwv  = wsf + CW_OFF;
  float* scal = wsf + SCAL_OFF;

  k_pre<<<dim3(704), 256, 0, stream>>>(Wq, Wk, Wv, Wfc, x, (unsigned*)Wb, xsT);
  k_qkv_mfma<<<dim3(24, 8, 3), 256, 0, stream>>>(Wb, bq, bk, bv, xsT, Qbf, Kbf, Vt);
  k_attn_mfma<<<dim3(1336), 256, 0, stream>>>(Qbf, Kbf, Vt, Obf, wsf);
  k_combine<<<dim3(90), 256, 0, stream>>>(wsf, Obf);
  k_fc_mfma<<<dim3(24, 8), 256, 0, stream>>>(Wb + 196608, bfc, Obf, Yb);
  k_upstats<<<dim3(256), 256, 0, stream>>>(Yb, x, outa, st);
  k_se<<<dim3(1), 256, 0, stream>>>(st, w1, b1, a1, w2, b2, cwv, scal);
  k_final<<<dim3(NLN / 256), 256, 0, stream>>>(outa, x, cwv, scal, a2, (float*)d_out);
}